// Round 4
// baseline (253.448 us; speedup 1.0000x reference)
//
#include <hip/hip_runtime.h>

#define NB 32
#define NL 512
#define ND 512
#define NH 1024
#define NE 8
#define NROWS (NB * NL)       // 16384
#define NTILES (NROWS / 64)   // 256

typedef __attribute__((ext_vector_type(8))) short bf16x8;
typedef __attribute__((ext_vector_type(4))) float f32x4;

__device__ __forceinline__ unsigned short f2bf(float f) {
    unsigned u = __float_as_uint(f);
    return (unsigned short)((u + 0x7fffu + ((u >> 16) & 1u)) >> 16);
}
__device__ __forceinline__ float bf2f(unsigned short b) {
    return __uint_as_float(((unsigned)b) << 16);
}
__device__ __forceinline__ unsigned pack2(float a0, float a1, unsigned& lo) {
    unsigned short h0 = f2bf(a0), h1 = f2bf(a1);
    unsigned short l0 = f2bf(a0 - bf2f(h0)), l1 = f2bf(a1 - bf2f(h1));
    lo = ((unsigned)l1 << 16) | l0;
    return ((unsigned)h1 << 16) | h0;
}

// ---------- W prep: transpose + split, packed [nt][kb][lane][jp] ----------
__global__ __launch_bounds__(256) void wprep(
    const float* __restrict__ Wt, const float* __restrict__ Ws,
    unsigned* __restrict__ bpack)
{
    __shared__ float tile[64][65];
    int bid = blockIdx.x;
    int mat = bid >> 7, rem = bid & 127;
    int kt0 = (rem >> 4) << 6;
    int nt0 = (rem & 15) << 6;
    const float* W = mat ? Ws : Wt;
    unsigned* Oh = bpack + (mat ? 2u : 0u) * 262144u;
    unsigned* Ol = Oh + 262144u;
    int t = threadIdx.x;
    #pragma unroll
    for (int i = 0; i < 16; ++i) {
        int idx = t + 256 * i;
        int k = idx >> 6, n = idx & 63;
        tile[k][n] = W[(size_t)(kt0 + k) * NH + nt0 + n];
    }
    __syncthreads();
    #pragma unroll
    for (int i = 0; i < 8; ++i) {
        int idx = t + 256 * i;                 // 2048 u32 positions
        int jp = idx & 3, lane = (idx >> 2) & 63, kbr = (idx >> 8) & 1, ntr = (idx >> 9) & 3;
        int ncol = ntr * 16 + (lane & 15);
        int kcol = kbr * 32 + ((lane >> 4) << 3) + jp * 2;
        float w0 = tile[kcol][ncol], w1 = tile[kcol + 1][ncol];
        unsigned lo, hi = pack2(w0, w1, lo);
        int nt = (nt0 >> 4) + ntr;
        int kb = (kt0 >> 5) + kbr;
        unsigned offs = ((unsigned)(nt * 16 + kb) * 64u + (unsigned)lane) * 4u + jp;
        Oh[offs] = hi;
        Ol[offs] = lo;
    }
}

// ---------- A prep: decomp (sliding MA) + split, fragment-packed per tile ----------
__global__ __launch_bounds__(256) void aprep(
    const float* __restrict__ x, unsigned* __restrict__ apack, int t0)
{
    __shared__ float xt[88][131];
    __shared__ float ma[64][131];
    int tile = t0 + blockIdx.x;
    int row0 = tile * 64;
    int b = row0 >> 9, l0 = row0 & (NL - 1);
    const float* xb = x + (size_t)b * NL * ND;
    unsigned* base = apack + (size_t)blockIdx.x * 65536u;
    int tid = threadIdx.x;

    for (int kc = 0; kc < 4; ++kc) {
        int k0 = kc * 128;
        __syncthreads();
        #pragma unroll
        for (int i = 0; i < 44; ++i) {
            int idx = tid + 256 * i;          // 88*128 = 11264
            int rr = idx >> 7, cc = idx & 127;
            int ll = l0 - 12 + rr;
            ll = ll < 0 ? 0 : (ll > NL - 1 ? NL - 1 : ll);
            xt[rr][cc] = xb[(size_t)ll * ND + k0 + cc];
        }
        __syncthreads();
        {   // sliding 25-tap window along rows
            int cc = tid & 127, half = tid >> 7;
            int r0 = half * 32;
            float s = 0.f;
            #pragma unroll
            for (int t = 0; t < 25; ++t) s += xt[r0 + t][cc];
            ma[r0][cc] = s * (1.f / 25.f);
            for (int r = r0 + 1; r < r0 + 32; ++r) {
                s += xt[r + 24][cc] - xt[r - 1][cc];
                ma[r][cc] = s * (1.f / 25.f);
            }
        }
        __syncthreads();
        #pragma unroll
        for (int i = 0; i < 16; ++i) {
            int idx = tid + 256 * i;          // 4096 u32 per array
            int jp = idx & 3, lane = (idx >> 2) & 63, mf = (idx >> 8) & 3, kbr = (idx >> 10) & 3;
            int row = mf * 16 + (lane & 15);
            int kr = kbr * 32 + ((lane >> 4) << 3) + jp * 2;
            float m0 = ma[row][kr], m1 = ma[row][kr + 1];
            float x0 = xt[row + 12][kr], x1 = xt[row + 12][kr + 1];
            unsigned tlo, thi = pack2(x0 - m0, x1 - m1, tlo);
            unsigned slo, shi = pack2(m0, m1, slo);
            int kb = kc * 4 + kbr;
            unsigned offs = ((unsigned)(kb * 4 + mf) * 64u + (unsigned)lane) * 4u + jp;
            base[offs]          = thi;
            base[16384u + offs] = tlo;
            base[32768u + offs] = shi;
            base[49152u + offs] = slo;
        }
    }
}

// ---------- pipelined half-GEMM: 16 kb, 1-deep register double-buffer ----------
__device__ __forceinline__ void gemm_half(
    const unsigned* __restrict__ Ah, const unsigned* __restrict__ Al,
    const unsigned* __restrict__ Bh, const unsigned* __restrict__ Bl,
    unsigned lane, unsigned ntbase, f32x4 (&acc)[4][4])
{
    bf16x8 ah0[4], al0[4], bh0[4], bl0[4];
    bf16x8 ah1[4], al1[4], bh1[4], bl1[4];

#define LOADK(KB, AH, AL, BH, BL)                                         \
    _Pragma("unroll")                                                     \
    for (int mf = 0; mf < 4; ++mf) {                                      \
        unsigned ao = (((KB) * 4u + (unsigned)mf) * 64u + lane) * 4u;     \
        AH[mf] = *(const bf16x8*)(Ah + ao);                               \
        AL[mf] = *(const bf16x8*)(Al + ao);                               \
    }                                                                     \
    _Pragma("unroll")                                                     \
    for (int cf = 0; cf < 4; ++cf) {                                      \
        unsigned bo = (((ntbase + (unsigned)cf) * 16u + (KB)) * 64u + lane) * 4u; \
        BH[cf] = *(const bf16x8*)(Bh + bo);                               \
        BL[cf] = *(const bf16x8*)(Bl + bo);                               \
    }

#define MFMAK(AH, AL, BH, BL)                                             \
    _Pragma("unroll")                                                     \
    for (int cf = 0; cf < 4; ++cf)                                        \
        _Pragma("unroll")                                                 \
        for (int mf = 0; mf < 4; ++mf) {                                  \
            acc[cf][mf] = __builtin_amdgcn_mfma_f32_16x16x32_bf16(AH[mf], BH[cf], acc[cf][mf], 0, 0, 0); \
            acc[cf][mf] = __builtin_amdgcn_mfma_f32_16x16x32_bf16(AL[mf], BH[cf], acc[cf][mf], 0, 0, 0); \
            acc[cf][mf] = __builtin_amdgcn_mfma_f32_16x16x32_bf16(AH[mf], BL[cf], acc[cf][mf], 0, 0, 0); \
        }

    #pragma unroll
    for (int cf = 0; cf < 4; ++cf)
        #pragma unroll
        for (int mf = 0; mf < 4; ++mf)
            acc[cf][mf] = (f32x4){0.f, 0.f, 0.f, 0.f};

    LOADK(0u, ah0, al0, bh0, bl0)
    #pragma unroll 1
    for (unsigned kb = 0; kb < 14; kb += 2) {
        LOADK(kb + 1u, ah1, al1, bh1, bl1)
        MFMAK(ah0, al0, bh0, bl0)
        LOADK(kb + 2u, ah0, al0, bh0, bl0)
        MFMAK(ah1, al1, bh1, bl1)
    }
    LOADK(15u, ah1, al1, bh1, bl1)
    MFMAK(ah0, al0, bh0, bl0)
    MFMAK(ah1, al1, bh1, bl1)
#undef LOADK
#undef MFMAK
}

// ---------- GEMM pass: 512 thr / 8 waves, full N via two sequential halves ----------
template<int PASS>
__global__ __launch_bounds__(512, 2) void gemm_pass(
    unsigned* __restrict__ apack, const unsigned* __restrict__ bpack,
    const float* __restrict__ bias, const float* __restrict__ gam, const float* __restrict__ bet,
    const float* __restrict__ W2, const float* __restrict__ b2,
    unsigned* __restrict__ mb, float* __restrict__ gates, int t0)
{
    __shared__ float hstash[64][516];        // 132096 B: raw h of N-half 0 (padded)
    __shared__ float stats[2][8][64][2];     //   8192 B
    __shared__ float rowstat[64][2];         //    512 B
    __shared__ float lgp[8][64][NE];         //  16384 B

    const int tid = threadIdx.x, lane = tid & 63, wave = tid >> 6;
    const int g = lane >> 4, c = lane & 15;
    const int ltile = blockIdx.x;
    const int tile = t0 + ltile;
    const int row0 = tile * 64;
    const int b = row0 >> 9, l0 = row0 & (NL - 1);

    const unsigned* Ah = apack + (size_t)ltile * 65536u + (PASS ? 32768u : 0u);
    const unsigned* Al = Ah + 16384u;
    const unsigned* Bh = bpack + (PASS ? 524288u : 0u);
    const unsigned* Bl = Bh + 262144u;
    unsigned short* tstash = (unsigned short*)(apack + (size_t)ltile * 65536u);

    f32x4 acc[4][4];

    auto do_stats = [&](int half) {
        #pragma unroll
        for (int cf = 0; cf < 4; ++cf) {
            float bv = bias[half * 512 + wave * 64 + cf * 16 + c];
            #pragma unroll
            for (int mf = 0; mf < 4; ++mf)
                #pragma unroll
                for (int r = 0; r < 4; ++r) acc[cf][mf][r] += bv;
        }
        #pragma unroll
        for (int mf = 0; mf < 4; ++mf)
            #pragma unroll
            for (int r = 0; r < 4; ++r) {
                float s = 0.f, q = 0.f;
                #pragma unroll
                for (int cf = 0; cf < 4; ++cf) { float v = acc[cf][mf][r]; s += v; q += v * v; }
                #pragma unroll
                for (int o = 1; o < 16; o <<= 1) { s += __shfl_xor(s, o); q += __shfl_xor(q, o); }
                if (c == 0) {
                    int row = mf * 16 + g * 4 + r;
                    stats[half][wave][row][0] = s;
                    stats[half][wave][row][1] = q;
                }
            }
    };

    // ---- N-half 0: k-loop, stats, dump raw h to LDS ----
    gemm_half(Ah, Al, Bh, Bl, (unsigned)lane, (unsigned)(wave * 4), acc);
    do_stats(0);
    #pragma unroll
    for (int cf = 0; cf < 4; ++cf)
        #pragma unroll
        for (int mf = 0; mf < 4; ++mf)
            #pragma unroll
            for (int r = 0; r < 4; ++r)
                hstash[mf * 16 + g * 4 + r][wave * 64 + cf * 16 + c] = acc[cf][mf][r];

    // ---- N-half 1: k-loop, stats ----
    gemm_half(Ah, Al, Bh, Bl, (unsigned)lane, (unsigned)(32 + wave * 4), acc);
    do_stats(1);
    __syncthreads();

    if (tid < 64) {
        float s = 0.f, q = 0.f;
        #pragma unroll
        for (int h = 0; h < 2; ++h)
            #pragma unroll
            for (int w = 0; w < 8; ++w) { s += stats[h][w][tid][0]; q += stats[h][w][tid][1]; }
        float mu = s * (1.f / NH);
        float var = q * (1.f / NH) - mu * mu;
        rowstat[tid][0] = mu;
        rowstat[tid][1] = rsqrtf(var + 1e-5f);
    }
    __syncthreads();

    if (PASS == 0) {
        float gv0[4], gv1[4], bev0[4], bev1[4];
        #pragma unroll
        for (int cf = 0; cf < 4; ++cf) {
            int nl = wave * 64 + cf * 16 + c;
            gv0[cf] = gam[nl];       bev0[cf] = bet[nl];
            gv1[cf] = gam[512 + nl]; bev1[cf] = bet[512 + nl];
        }
        #pragma unroll
        for (int mf = 0; mf < 4; ++mf)
            #pragma unroll
            for (int r = 0; r < 4; ++r) {
                int row = mf * 16 + g * 4 + r;
                float mu = rowstat[row][0], rs = rowstat[row][1];
                #pragma unroll
                for (int cf = 0; cf < 4; ++cf) {
                    int nl = wave * 64 + cf * 16 + c;
                    tstash[row * 1024 + nl]       = f2bf((hstash[row][nl] - mu) * rs * gv0[cf] + bev0[cf]);
                    tstash[row * 1024 + 512 + nl] = f2bf((acc[cf][mf][r] - mu) * rs * gv1[cf] + bev1[cf]);
                }
            }
    } else {
        float gv0[4], gv1[4], bev0[4], bev1[4];
        float w2v0[4][NE], w2v1[4][NE];
        #pragma unroll
        for (int cf = 0; cf < 4; ++cf) {
            int nl = wave * 64 + cf * 16 + c;
            gv0[cf] = gam[nl];       bev0[cf] = bet[nl];
            gv1[cf] = gam[512 + nl]; bev1[cf] = bet[512 + nl];
            const float4* wp0 = (const float4*)&W2[(size_t)nl * NE];
            const float4* wp1 = (const float4*)&W2[(size_t)(512 + nl) * NE];
            float4 a0 = wp0[0], a1 = wp0[1], b0 = wp1[0], b1 = wp1[1];
            w2v0[cf][0] = a0.x; w2v0[cf][1] = a0.y; w2v0[cf][2] = a0.z; w2v0[cf][3] = a0.w;
            w2v0[cf][4] = a1.x; w2v0[cf][5] = a1.y; w2v0[cf][6] = a1.z; w2v0[cf][7] = a1.w;
            w2v1[cf][0] = b0.x; w2v1[cf][1] = b0.y; w2v1[cf][2] = b0.z; w2v1[cf][3] = b0.w;
            w2v1[cf][4] = b1.x; w2v1[cf][5] = b1.y; w2v1[cf][6] = b1.z; w2v1[cf][7] = b1.w;
        }
        #pragma unroll
        for (int mf = 0; mf < 4; ++mf)
            #pragma unroll
            for (int r = 0; r < 4; ++r) {
                int row = mf * 16 + g * 4 + r;
                float mu = rowstat[row][0], rs = rowstat[row][1];
                float lg[NE];
                #pragma unroll
                for (int e = 0; e < NE; ++e) lg[e] = 0.f;
                #pragma unroll
                for (int cf = 0; cf < 4; ++cf) {
                    int nl = wave * 64 + cf * 16 + c;
                    float s0 = (hstash[row][nl] - mu) * rs * gv0[cf] + bev0[cf];
                    float t0v = bf2f(tstash[row * 1024 + nl]);
                    float m0 = t0v + s0; m0 = m0 > 0.f ? m0 : 0.f;
                    float s1 = (acc[cf][mf][r] - mu) * rs * gv1[cf] + bev1[cf];
                    float t1v = bf2f(tstash[row * 1024 + 512 + nl]);
                    float m1 = t1v + s1; m1 = m1 > 0.f ? m1 : 0.f;
                    #pragma unroll
                    for (int e = 0; e < NE; ++e)
                        lg[e] = fmaf(m0, w2v0[cf][e], fmaf(m1, w2v1[cf][e], lg[e]));
                }
                #pragma unroll
                for (int o = 1; o < 16; o <<= 1)
                    #pragma unroll
                    for (int e = 0; e < NE; ++e) lg[e] += __shfl_xor(lg[e], o);
                if (c == 0)
                    #pragma unroll
                    for (int e = 0; e < NE; ++e) lgp[wave][row][e] = lg[e];
            }
        __syncthreads();
        if (tid < 64) {
            float lg[NE];
            #pragma unroll
            for (int e = 0; e < NE; ++e) {
                float s = b2[e];
                #pragma unroll
                for (int w = 0; w < 8; ++w) s += lgp[w][tid][e];
                lg[e] = s;
            }
            float mx = lg[0];
            #pragma unroll
            for (int e = 1; e < NE; ++e) mx = lg[e] > mx ? lg[e] : mx;
            float p[NE]; float sum = 0.f;
            #pragma unroll
            for (int e = 0; e < NE; ++e) { p[e] = expf(lg[e] - mx); sum += p[e]; }
            float inv = 1.f / sum;
            int i0 = 0;
            #pragma unroll
            for (int e = 1; e < NE; ++e) if (lg[e] > lg[i0]) i0 = e;
            int i1 = i0 == 0 ? 1 : 0;
            #pragma unroll
            for (int e = 0; e < NE; ++e) if (e != i0 && lg[e] > lg[i1]) i1 = e;
            atomicOr(&mb[2 * b + 0], 1u << i0);
            atomicOr(&mb[2 * b + 1], 1u << i1);
            if (l0 == 0 && tid < 8) {
                #pragma unroll
                for (int e = 0; e < NE; ++e)
                    gates[((size_t)b * 8 + tid) * NE + e] = p[e] * inv;
            }
        }
    }
}

// masked = gates * maskbit; denom = sum_b + 1e-4; out = masked/denom*64
__global__ void finalize_k(const unsigned* __restrict__ mb,
                           const float* __restrict__ gates,
                           float* __restrict__ out)
{
    int t = threadIdx.x;
    if (t >= 16) return;
    int l = t >> 1, e = t & 1;
    float m[NB];
    float sum = 0.f;
    #pragma unroll
    for (int bb = 0; bb < NB; ++bb) {
        float gvv = gates[((size_t)bb * 8 + l) * NE + e];
        float on  = ((mb[2 * bb + e] >> l) & 1u) ? 1.f : 0.f;
        m[bb] = gvv * on;
        sum += m[bb];
    }
    float scale = 64.f / (sum + 1e-4f);   // capacity = int(2.0*32)
    #pragma unroll
    for (int bb = 0; bb < NB; ++bb)
        out[(size_t)bb * (NL * NE) + l * NE + e] = m[bb] * scale;
}

extern "C" void kernel_launch(void* const* d_in, const int* in_sizes, int n_in,
                              void* d_out, int out_size, void* d_ws, size_t ws_size,
                              hipStream_t stream) {
    const float* x   = (const float*)d_in[0];
    const float* Wt  = (const float*)d_in[1];
    const float* bt  = (const float*)d_in[2];
    const float* gt  = (const float*)d_in[3];
    const float* bet = (const float*)d_in[4];
    const float* Ws  = (const float*)d_in[5];
    const float* bs  = (const float*)d_in[6];
    const float* gs  = (const float*)d_in[7];
    const float* bes = (const float*)d_in[8];
    const float* W2  = (const float*)d_in[9];
    const float* b2  = (const float*)d_in[10];
    float* out = (float*)d_out;

    char* wsb = (char*)d_ws;
    unsigned* mb    = (unsigned*)wsb;                       // 256 B
    float*    gates = (float*)(wsb + 256);                  // 2 KB
    unsigned* bpack = (unsigned*)(wsb + 4096);              // 4 MiB
    unsigned* apack = (unsigned*)(wsb + 4096 + 4194304);    // up to 64 MiB

    size_t head = 4096 + 4194304;
    size_t avail = ws_size > head ? ws_size - head : 0;
    int tpp = (int)(avail / 262144);                        // 256 KiB per tile
    if (tpp > NTILES) tpp = NTILES;
    if (tpp < 1) tpp = 1;

    hipMemsetAsync(d_out, 0, sizeof(float) * NB * NL * NE, stream);
    hipMemsetAsync(mb, 0, 256, stream);

    wprep<<<256, 256, 0, stream>>>(Wt, Ws, bpack);
    for (int tptr = 0; tptr < NTILES; tptr += tpp) {
        int nt = NTILES - tptr < tpp ? NTILES - tptr : tpp;
        aprep<<<nt, 256, 0, stream>>>(x, apack, tptr);
        gemm_pass<0><<<nt, 512, 0, stream>>>(apack, bpack, bt, gt, bet, W2, b2, mb, gates, tptr);
        gemm_pass<1><<<nt, 512, 0, stream>>>(apack, bpack, bs, gs, bes, W2, b2, mb, gates, tptr);
    }
    finalize_k<<<1, 64, 0, stream>>>(mb, gates, out);
}